// Round 1
// baseline (597.646 us; speedup 1.0000x reference)
//
#include <hip/hip_runtime.h>

#define N_NODES 50000
#define N_EDGES 640000
#define D_IN    128
#define D_HID   256
#define D_OUT   128

// ---------------- CSR build ----------------

__global__ __launch_bounds__(256) void hist_kernel(const int* __restrict__ dst,
                                                   int* __restrict__ counts) {
    int e = blockIdx.x * 256 + threadIdx.x;
    if (e < N_EDGES) {
        unsigned d = (unsigned)dst[e];
        if (d < N_NODES) atomicAdd(&counts[d], 1);
    }
}

__global__ __launch_bounds__(1024) void scan_kernel(const int* __restrict__ counts,
                                                    int* __restrict__ offsets) {
    __shared__ int sums[1024];
    const int t = threadIdx.x;
    const int CH = (N_NODES + 1023) / 1024;  // 49
    int lo = t * CH, hi = lo + CH;
    if (lo > N_NODES) lo = N_NODES;
    if (hi > N_NODES) hi = N_NODES;
    int s = 0;
    for (int i = lo; i < hi; ++i) s += counts[i];
    sums[t] = s;
    __syncthreads();
    for (int off = 1; off < 1024; off <<= 1) {
        int add = (t >= off) ? sums[t - off] : 0;
        __syncthreads();
        sums[t] += add;
        __syncthreads();
    }
    int run = (t > 0) ? sums[t - 1] : 0;
    for (int i = lo; i < hi; ++i) { offsets[i] = run; run += counts[i]; }
    if (hi == N_NODES) offsets[N_NODES] = run;
}

__global__ __launch_bounds__(256) void scatter_kernel(const int* __restrict__ src,
                                                      const int* __restrict__ dst,
                                                      const int* __restrict__ offsets,
                                                      int* __restrict__ cursor,
                                                      int* __restrict__ elist) {
    int e = blockIdx.x * 256 + threadIdx.x;
    if (e < N_EDGES) {
        unsigned d = (unsigned)dst[e];
        unsigned s = (unsigned)src[e];
        if (d < N_NODES && s < N_NODES) {
            int pos = offsets[d] + atomicAdd(&cursor[d], 1);
            elist[pos] = (int)s;
        }
    }
}

// ---------------- aggregation: out[n] = xin[n] + sum_{e: dst=n} xin[src(e)] ----------------

template <int D>
__global__ __launch_bounds__(256) void aggregate_kernel(const float* __restrict__ xin,
                                                        const int* __restrict__ offsets,
                                                        const int* __restrict__ elist,
                                                        float* __restrict__ out) {
    constexpr int L = D / 4;        // lanes per node (float4 per lane)
    constexpr int G = 256 / L;      // nodes per block
    const int g = threadIdx.x / L;
    const int l = threadIdx.x % L;
    const int node = blockIdx.x * G + g;
    if (node >= N_NODES) return;
    const float4* xr = (const float4*)(xin + (size_t)node * D);
    float4 acc = xr[l];
    const int beg = offsets[node], end = offsets[node + 1];
    for (int i = beg; i < end; ++i) {
        int s = elist[i];
        const float4 v = ((const float4*)(xin + (size_t)s * D))[l];
        acc.x += v.x; acc.y += v.y; acc.z += v.z; acc.w += v.w;
    }
    ((float4*)(out + (size_t)node * D))[l] = acc;
}

// ---------------- fp32 tiled GEMM: C = [ReLU](A @ W + b) ----------------
// A: MxK row-major, W: KxN row-major, C: MxN row-major. N % 64 == 0, K % 32 == 0.

template <bool RELU>
__global__ __launch_bounds__(256) void gemm_bias(const float* __restrict__ A,
                                                 const float* __restrict__ W,
                                                 const float* __restrict__ bias,
                                                 float* __restrict__ C,
                                                 int M, int N, int K) {
    constexpr int BM = 128, BN = 64, BK = 32;
    __shared__ float As[BK][BM + 4];   // A tile transposed: As[k][m]
    __shared__ float Ws[BK][BN + 4];   // W tile: Ws[k][n]
    const int tid = threadIdx.x;
    const int tx = tid & 15;           // 0..15 -> 4 cols each
    const int ty = tid >> 4;           // 0..15 -> 8 rows each
    const int row0 = blockIdx.y * BM;
    const int col0 = blockIdx.x * BN;
    const int ar = tid >> 3;           // 0..31
    const int ak = (tid & 7) << 2;     // 0,4,...,28
    const int wr = tid >> 4;           // 0..15
    const int wc = (tid & 15) << 2;    // 0..60

    float acc[8][4];
#pragma unroll
    for (int i = 0; i < 8; ++i)
#pragma unroll
        for (int j = 0; j < 4; ++j) acc[i][j] = 0.f;

    for (int k0 = 0; k0 < K; k0 += BK) {
#pragma unroll
        for (int i = 0; i < 4; ++i) {
            int r = ar + i * 32;
            int grow = row0 + r;
            float4 v = make_float4(0.f, 0.f, 0.f, 0.f);
            if (grow < M) v = *(const float4*)(A + (size_t)grow * K + (k0 + ak));
            As[ak + 0][r] = v.x; As[ak + 1][r] = v.y;
            As[ak + 2][r] = v.z; As[ak + 3][r] = v.w;
        }
#pragma unroll
        for (int i = 0; i < 2; ++i) {
            int r = wr + i * 16;
            float4 v = *(const float4*)(W + (size_t)(k0 + r) * N + (col0 + wc));
            *(float4*)(&Ws[r][wc]) = v;
        }
        __syncthreads();
#pragma unroll
        for (int k = 0; k < BK; ++k) {
            float4 a0 = *(const float4*)(&As[k][ty * 8]);
            float4 a1 = *(const float4*)(&As[k][ty * 8 + 4]);
            float4 b  = *(const float4*)(&Ws[k][tx * 4]);
            float aa[8] = {a0.x, a0.y, a0.z, a0.w, a1.x, a1.y, a1.z, a1.w};
            float bb[4] = {b.x, b.y, b.z, b.w};
#pragma unroll
            for (int i = 0; i < 8; ++i)
#pragma unroll
                for (int j = 0; j < 4; ++j) acc[i][j] += aa[i] * bb[j];
        }
        __syncthreads();
    }

    float4 bv = *(const float4*)(bias + col0 + tx * 4);
    float bb4[4] = {bv.x, bv.y, bv.z, bv.w};
#pragma unroll
    for (int i = 0; i < 8; ++i) {
        int grow = row0 + ty * 8 + i;
        if (grow < M) {
            float4 o;
            o.x = acc[i][0] + bb4[0];
            o.y = acc[i][1] + bb4[1];
            o.z = acc[i][2] + bb4[2];
            o.w = acc[i][3] + bb4[3];
            if (RELU) {
                o.x = fmaxf(o.x, 0.f); o.y = fmaxf(o.y, 0.f);
                o.z = fmaxf(o.z, 0.f); o.w = fmaxf(o.w, 0.f);
            }
            *(float4*)(C + (size_t)grow * N + (col0 + tx * 4)) = o;
        }
    }
}

// ---------------- launch ----------------

extern "C" void kernel_launch(void* const* d_in, const int* in_sizes, int n_in,
                              void* d_out, int out_size, void* d_ws, size_t ws_size,
                              hipStream_t stream) {
    const float* x   = (const float*)d_in[0];
    const int*   ei  = (const int*)d_in[1];         // [2][N_EDGES]: row0=src, row1=dst
    const float* W1a = (const float*)d_in[2];
    const float* b1a = (const float*)d_in[3];
    const float* W1b = (const float*)d_in[4];
    const float* b1b = (const float*)d_in[5];
    const float* W2a = (const float*)d_in[6];
    const float* b2a = (const float*)d_in[7];
    const float* W2b = (const float*)d_in[8];
    const float* b2b = (const float*)d_in[9];
    float* out = (float*)d_out;

    const int* src = ei;
    const int* dst = ei + N_EDGES;

    // workspace layout
    int* counts  = (int*)d_ws;                    // N_NODES
    int* cursor  = counts + N_NODES;              // N_NODES
    int* offsets = cursor + N_NODES;              // N_NODES+1
    int* elist   = offsets + (N_NODES + 1);       // N_EDGES
    size_t int_bytes = (size_t)(2 * N_NODES + N_NODES + 1 + N_EDGES) * sizeof(int);
    size_t foff = (int_bytes + 255) & ~(size_t)255;
    float* hA = (float*)((char*)d_ws + foff);     // N_NODES*256
    float* hB = hA + (size_t)N_NODES * D_HID;     // N_NODES*256
    float* hC = hB + (size_t)N_NODES * D_HID;     // N_NODES*256
    float* h0 = hC;                               // aliased: used (128-d) before hC written

    hipMemsetAsync(counts, 0, (size_t)2 * N_NODES * sizeof(int), stream);

    const int eb = (N_EDGES + 255) / 256;
    hist_kernel<<<eb, 256, 0, stream>>>(dst, counts);
    scan_kernel<<<1, 1024, 0, stream>>>(counts, offsets);
    scatter_kernel<<<eb, 256, 0, stream>>>(src, dst, offsets, cursor, elist);

    // conv1: h0 = x + agg(x)  (128-d), 8 nodes/block
    aggregate_kernel<128><<<(N_NODES + 7) / 8, 256, 0, stream>>>(x, offsets, elist, h0);
    // hA = relu(h0 @ W1a + b1a)   [50000 x 256]
    gemm_bias<true><<<dim3(D_HID / 64, (N_NODES + 127) / 128), 256, 0, stream>>>(
        h0, W1a, b1a, hA, N_NODES, D_HID, D_IN);
    // hB = relu(hA @ W1b + b1b)   (outer ReLU fused)
    gemm_bias<true><<<dim3(D_HID / 64, (N_NODES + 127) / 128), 256, 0, stream>>>(
        hA, W1b, b1b, hB, N_NODES, D_HID, D_HID);
    // conv2: hC = hB + agg(hB)  (256-d), 4 nodes/block
    aggregate_kernel<256><<<(N_NODES + 3) / 4, 256, 0, stream>>>(hB, offsets, elist, hC);
    // hA = relu(hC @ W2a + b2a)
    gemm_bias<true><<<dim3(D_HID / 64, (N_NODES + 127) / 128), 256, 0, stream>>>(
        hC, W2a, b2a, hA, N_NODES, D_HID, D_HID);
    // out = hA @ W2b + b2b
    gemm_bias<false><<<dim3(D_OUT / 64, (N_NODES + 127) / 128), 256, 0, stream>>>(
        hA, W2b, b2b, out, N_NODES, D_OUT, D_HID);
}

// Round 2
// 466.281 us; speedup vs baseline: 1.2817x; 1.2817x over previous
//
#include <hip/hip_runtime.h>

#define N_NODES 50000
#define N_EDGES 640000
#define D_IN    128
#define D_HID   256
#define D_OUT   128

typedef __attribute__((ext_vector_type(8))) short bf16x8;
typedef __attribute__((ext_vector_type(4))) float f32x4;

// ---- hi/lo bf16 packing: uint32 = (hi bf16 in low16) | (lo bf16 in high16) ----
__device__ inline unsigned packhl(float f) {
    unsigned u = __builtin_bit_cast(unsigned, f);
    unsigned hb = u & 0xffff0000u;                       // truncated-hi bits
    float rem = f - __builtin_bit_cast(float, hb);
    unsigned rl = __builtin_bit_cast(unsigned, rem);
    return (u >> 16) | (rl & 0xffff0000u);
}
__device__ inline float unpackhl(unsigned p) {
    return __builtin_bit_cast(float, p << 16) +
           __builtin_bit_cast(float, p & 0xffff0000u);
}

// ---------------- CSR build ----------------

__global__ __launch_bounds__(256) void hist_kernel(const int* __restrict__ dst,
                                                   int* __restrict__ counts) {
    int e = blockIdx.x * 256 + threadIdx.x;
    if (e < N_EDGES) {
        unsigned d = (unsigned)dst[e];
        if (d < N_NODES) atomicAdd(&counts[d], 1);
    }
}

__global__ __launch_bounds__(1024) void scan_kernel(const int* __restrict__ counts,
                                                    int* __restrict__ offsets) {
    __shared__ int sums[1024];
    const int t = threadIdx.x;
    const int CH = (N_NODES + 1023) / 1024;
    int lo = t * CH, hi = lo + CH;
    if (lo > N_NODES) lo = N_NODES;
    if (hi > N_NODES) hi = N_NODES;
    int s = 0;
    for (int i = lo; i < hi; ++i) s += counts[i];
    sums[t] = s;
    __syncthreads();
    for (int off = 1; off < 1024; off <<= 1) {
        int add = (t >= off) ? sums[t - off] : 0;
        __syncthreads();
        sums[t] += add;
        __syncthreads();
    }
    int run = (t > 0) ? sums[t - 1] : 0;
    for (int i = lo; i < hi; ++i) { offsets[i] = run; run += counts[i]; }
    if (hi == N_NODES) offsets[N_NODES] = run;
}

__global__ __launch_bounds__(256) void scatter_kernel(const int* __restrict__ src,
                                                      const int* __restrict__ dst,
                                                      const int* __restrict__ offsets,
                                                      int* __restrict__ cursor,
                                                      int* __restrict__ elist) {
    int e = blockIdx.x * 256 + threadIdx.x;
    if (e < N_EDGES) {
        unsigned d = (unsigned)dst[e];
        unsigned s = (unsigned)src[e];
        if (d < N_NODES && s < N_NODES) {
            int pos = offsets[d] + atomicAdd(&cursor[d], 1);
            elist[pos] = (int)s;
        }
    }
}

// ---------------- weight decompose+transpose: W[K][N] fp32 -> Wt hi/lo planes [N][K] bf16 ----

__global__ __launch_bounds__(256) void decomp_w(const float* __restrict__ W, int K, int N,
                                                ushort* __restrict__ hi, ushort* __restrict__ lo) {
    int idx = blockIdx.x * 256 + threadIdx.x;
    if (idx >= K * N) return;
    int n = idx / K, k = idx - n * K;
    float f = W[(size_t)k * N + n];
    unsigned u = __builtin_bit_cast(unsigned, f);
    unsigned hb = u & 0xffff0000u;
    float rem = f - __builtin_bit_cast(float, hb);
    hi[idx] = (ushort)(u >> 16);
    lo[idx] = (ushort)(__builtin_bit_cast(unsigned, rem) >> 16);
}

// ---------------- aggregation ----------------
// out[n] = pack( x[n] + sum_{e: dst=n} x[src(e)] ), x fp32 [N][128]
__global__ __launch_bounds__(256) void agg_f32_pk128(const float* __restrict__ x,
                                                     const int* __restrict__ offsets,
                                                     const int* __restrict__ elist,
                                                     unsigned* __restrict__ out) {
    const int l = threadIdx.x & 31;   // 32 lanes/node (float4)
    const int g = threadIdx.x >> 5;   // 8 nodes/block
    const int node = blockIdx.x * 8 + g;
    if (node >= N_NODES) return;
    float4 acc = ((const float4*)(x + (size_t)node * 128))[l];
    const int beg = offsets[node], end = offsets[node + 1];
    for (int i = beg; i < end; ++i) {
        int s = elist[i];
        float4 v = ((const float4*)(x + (size_t)s * 128))[l];
        acc.x += v.x; acc.y += v.y; acc.z += v.z; acc.w += v.w;
    }
    uint4 o = make_uint4(packhl(acc.x), packhl(acc.y), packhl(acc.z), packhl(acc.w));
    ((uint4*)(out + (size_t)node * 128))[l] = o;
}

// packed [N][256] -> packed [N][256]
__global__ __launch_bounds__(256) void agg_pk256(const unsigned* __restrict__ hin,
                                                 const int* __restrict__ offsets,
                                                 const int* __restrict__ elist,
                                                 unsigned* __restrict__ hout) {
    const int l = threadIdx.x & 63;   // 64 lanes/node (uint4)
    const int g = threadIdx.x >> 6;   // 4 nodes/block
    const int node = blockIdx.x * 4 + g;
    if (node >= N_NODES) return;
    uint4 p = ((const uint4*)(hin + (size_t)node * 256))[l];
    float a0 = unpackhl(p.x), a1 = unpackhl(p.y), a2 = unpackhl(p.z), a3 = unpackhl(p.w);
    const int beg = offsets[node], end = offsets[node + 1];
    for (int i = beg; i < end; ++i) {
        int s = elist[i];
        uint4 v = ((const uint4*)(hin + (size_t)s * 256))[l];
        a0 += unpackhl(v.x); a1 += unpackhl(v.y); a2 += unpackhl(v.z); a3 += unpackhl(v.w);
    }
    uint4 o = make_uint4(packhl(a0), packhl(a1), packhl(a2), packhl(a3));
    ((uint4*)(hout + (size_t)node * 256))[l] = o;
}

// ---------------- split-bf16 MFMA GEMM ----------------
// C = [ReLU](unpack(A) @ W + b);  A packed [M][K]; W given as hi/lo planes [N][K].
// tile 128x128, BK=64, 256 threads = 4 waves (2x2), 16x16x32 bf16 MFMA, 3 passes.

template <bool RELU, bool PACKOUT>
__global__ __launch_bounds__(256, 2) void gemm_hl(const unsigned* __restrict__ Apk,
                                                  const ushort* __restrict__ Bh_g,
                                                  const ushort* __restrict__ Bl_g,
                                                  const float* __restrict__ bias,
                                                  void* __restrict__ Cout,
                                                  int M, int N, int K) {
    __shared__ ushort Ah[128 * 64], Al[128 * 64], Bh[128 * 64], Bl[128 * 64];
    const int tid = threadIdx.x;
    const int lane = tid & 63;
    const int wid = tid >> 6;
    const int wm = wid >> 1, wn = wid & 1;
    const int row0 = blockIdx.y * 128;
    const int col0 = blockIdx.x * 128;

    f32x4 acc[4][4];
#pragma unroll
    for (int i = 0; i < 4; ++i)
#pragma unroll
        for (int j = 0; j < 4; ++j) acc[i][j] = (f32x4){0.f, 0.f, 0.f, 0.f};

    for (int k0 = 0; k0 < K; k0 += 64) {
        // stage A: 1024 tasks (row 0..127, kb 0..7), 8 elems each
#pragma unroll
        for (int i = 0; i < 4; ++i) {
            int t = tid + i * 256;
            int row = t >> 3, kb = t & 7;
            int grow = row0 + row;
            uint4 p0 = make_uint4(0u, 0u, 0u, 0u), p1 = p0;
            if (grow < M) {
                const uint4* s = (const uint4*)(Apk + (size_t)grow * K + (k0 + kb * 8));
                p0 = s[0]; p1 = s[1];
            }
            uint4 hw, lw;
            hw.x = (p0.x & 0xffffu) | (p0.y << 16);
            lw.x = (p0.x >> 16)     | (p0.y & 0xffff0000u);
            hw.y = (p0.z & 0xffffu) | (p0.w << 16);
            lw.y = (p0.z >> 16)     | (p0.w & 0xffff0000u);
            hw.z = (p1.x & 0xffffu) | (p1.y << 16);
            lw.z = (p1.x >> 16)     | (p1.y & 0xffff0000u);
            hw.w = (p1.z & 0xffffu) | (p1.w << 16);
            lw.w = (p1.z >> 16)     | (p1.w & 0xffff0000u);
            int off = ((row * 64 + kb * 8) * 2) ^ ((row & 7) << 4);
            *(uint4*)((char*)Ah + off) = hw;
            *(uint4*)((char*)Al + off) = lw;
        }
        // stage B: 1024 tasks (col 0..127, kb 0..7)
#pragma unroll
        for (int i = 0; i < 4; ++i) {
            int t = tid + i * 256;
            int col = t >> 3, kb = t & 7;
            size_t goff = (size_t)(col0 + col) * K + (k0 + kb * 8);
            uint4 h = *(const uint4*)(Bh_g + goff);
            uint4 l2 = *(const uint4*)(Bl_g + goff);
            int off = ((col * 64 + kb * 8) * 2) ^ ((col & 7) << 4);
            *(uint4*)((char*)Bh + off) = h;
            *(uint4*)((char*)Bl + off) = l2;
        }
        __syncthreads();
#pragma unroll
        for (int ki = 0; ki < 2; ++ki) {
            bf16x8 ah[4], al[4], bh[4], bl[4];
            const int kbyte = (ki * 32 + ((lane >> 4) * 8)) * 2;
#pragma unroll
            for (int mi = 0; mi < 4; ++mi) {
                int row = wm * 64 + mi * 16 + (lane & 15);
                int off = (row * 128 + kbyte) ^ ((row & 7) << 4);
                ah[mi] = *(const bf16x8*)((const char*)Ah + off);
                al[mi] = *(const bf16x8*)((const char*)Al + off);
            }
#pragma unroll
            for (int ni = 0; ni < 4; ++ni) {
                int col = wn * 64 + ni * 16 + (lane & 15);
                int off = (col * 128 + kbyte) ^ ((col & 7) << 4);
                bh[ni] = *(const bf16x8*)((const char*)Bh + off);
                bl[ni] = *(const bf16x8*)((const char*)Bl + off);
            }
#pragma unroll
            for (int mi = 0; mi < 4; ++mi)
#pragma unroll
                for (int ni = 0; ni < 4; ++ni) {
                    acc[mi][ni] = __builtin_amdgcn_mfma_f32_16x16x32_bf16(ah[mi], bh[ni], acc[mi][ni], 0, 0, 0);
                    acc[mi][ni] = __builtin_amdgcn_mfma_f32_16x16x32_bf16(ah[mi], bl[ni], acc[mi][ni], 0, 0, 0);
                    acc[mi][ni] = __builtin_amdgcn_mfma_f32_16x16x32_bf16(al[mi], bh[ni], acc[mi][ni], 0, 0, 0);
                }
        }
        __syncthreads();
    }
    // epilogue: C/D layout col=lane&15, row=(lane>>4)*4+r
#pragma unroll
    for (int ni = 0; ni < 4; ++ni) {
        int col = col0 + wn * 64 + ni * 16 + (lane & 15);
        float bv = bias[col];
#pragma unroll
        for (int mi = 0; mi < 4; ++mi) {
            int rowb = row0 + wm * 64 + mi * 16 + ((lane >> 4) << 2);
            f32x4 a = acc[mi][ni];
#pragma unroll
            for (int r = 0; r < 4; ++r) {
                int row = rowb + r;
                if (row < M) {
                    float f = a[r] + bv;
                    if (RELU) f = fmaxf(f, 0.f);
                    if (PACKOUT) ((unsigned*)Cout)[(size_t)row * N + col] = packhl(f);
                    else         ((float*)Cout)[(size_t)row * N + col] = f;
                }
            }
        }
    }
}

// ---------------- launch ----------------

extern "C" void kernel_launch(void* const* d_in, const int* in_sizes, int n_in,
                              void* d_out, int out_size, void* d_ws, size_t ws_size,
                              hipStream_t stream) {
    const float* x   = (const float*)d_in[0];
    const int*   ei  = (const int*)d_in[1];
    const float* W1a = (const float*)d_in[2];
    const float* b1a = (const float*)d_in[3];
    const float* W1b = (const float*)d_in[4];
    const float* b1b = (const float*)d_in[5];
    const float* W2a = (const float*)d_in[6];
    const float* b2a = (const float*)d_in[7];
    const float* W2b = (const float*)d_in[8];
    const float* b2b = (const float*)d_in[9];
    float* out = (float*)d_out;

    const int* src = ei;
    const int* dst = ei + N_EDGES;

    int* counts  = (int*)d_ws;
    int* cursor  = counts + N_NODES;
    int* offsets = cursor + N_NODES;
    int* elist   = offsets + (N_NODES + 1);

    size_t ob = (((size_t)(2 * N_NODES + N_NODES + 1 + N_EDGES) * 4) + 255) & ~(size_t)255;
    ushort* w1a_hi = (ushort*)((char*)d_ws + ob);
    ushort* w1a_lo = w1a_hi + 256 * 128;
    ushort* w1b_hi = w1a_lo + 256 * 128;
    ushort* w1b_lo = w1b_hi + 256 * 256;
    ushort* w2a_hi = w1b_lo + 256 * 256;
    ushort* w2a_lo = w2a_hi + 256 * 256;
    ushort* w2b_hi = w2a_lo + 256 * 256;
    ushort* w2b_lo = w2b_hi + 128 * 256;
    char*   wend   = (char*)(w2b_lo + 128 * 256);

    size_t fb = ((size_t)(wend - (char*)d_ws) + 255) & ~(size_t)255;
    unsigned* hA = (unsigned*)((char*)d_ws + fb);      // [N][256] packed
    unsigned* hB = hA + (size_t)N_NODES * 256;         // [N][256] packed
    unsigned* hC = hB + (size_t)N_NODES * 256;         // [N][256] packed
    unsigned* h0 = hC;                                 // [N][128] packed, aliased over hC

    hipMemsetAsync(counts, 0, (size_t)2 * N_NODES * sizeof(int), stream);

    const int eb = (N_EDGES + 255) / 256;
    hist_kernel<<<eb, 256, 0, stream>>>(dst, counts);
    scan_kernel<<<1, 1024, 0, stream>>>(counts, offsets);
    scatter_kernel<<<eb, 256, 0, stream>>>(src, dst, offsets, cursor, elist);

    decomp_w<<<(128 * 256 + 255) / 256, 256, 0, stream>>>(W1a, 128, 256, w1a_hi, w1a_lo);
    decomp_w<<<(256 * 256 + 255) / 256, 256, 0, stream>>>(W1b, 256, 256, w1b_hi, w1b_lo);
    decomp_w<<<(256 * 256 + 255) / 256, 256, 0, stream>>>(W2a, 256, 256, w2a_hi, w2a_lo);
    decomp_w<<<(256 * 128 + 255) / 256, 256, 0, stream>>>(W2b, 256, 128, w2b_hi, w2b_lo);

    // conv1 aggregate: h0 = pack(x + agg(x))   [N][128]
    agg_f32_pk128<<<(N_NODES + 7) / 8, 256, 0, stream>>>(x, offsets, elist, h0);
    // hA = pack(relu(h0 @ W1a + b1a))
    gemm_hl<true, true><<<dim3(2, (N_NODES + 127) / 128), 256, 0, stream>>>(
        h0, w1a_hi, w1a_lo, b1a, hA, N_NODES, 256, 128);
    // hB = pack(relu(hA @ W1b + b1b))   (outer ReLU fused)
    gemm_hl<true, true><<<dim3(2, (N_NODES + 127) / 128), 256, 0, stream>>>(
        hA, w1b_hi, w1b_lo, b1b, hB, N_NODES, 256, 256);
    // conv2 aggregate: hC = pack(hB + agg(hB))
    agg_pk256<<<(N_NODES + 3) / 4, 256, 0, stream>>>(hB, offsets, elist, hC);
    // hA = pack(relu(hC @ W2a + b2a))
    gemm_hl<true, true><<<dim3(2, (N_NODES + 127) / 128), 256, 0, stream>>>(
        hC, w2a_hi, w2a_lo, b2a, hA, N_NODES, 256, 256);
    // out = hA @ W2b + b2b   (fp32 out)
    gemm_hl<false, false><<<dim3(1, (N_NODES + 127) / 128), 256, 0, stream>>>(
        hA, w2b_hi, w2b_lo, b2b, out, N_NODES, 128, 256);
}

// Round 3
// 459.745 us; speedup vs baseline: 1.3000x; 1.0142x over previous
//
#include <hip/hip_runtime.h>

#define N_NODES 50000
#define N_EDGES 640000
#define D_IN    128
#define D_HID   256
#define D_OUT   128

typedef __attribute__((ext_vector_type(8))) short bf16x8;
typedef __attribute__((ext_vector_type(4))) float f32x4;

// ---- hi/lo bf16 packing: uint32 = (hi bf16 in low16) | (lo bf16 in high16) ----
__device__ inline unsigned packhl(float f) {
    unsigned u = __builtin_bit_cast(unsigned, f);
    unsigned hb = u & 0xffff0000u;                       // truncated-hi bits
    float rem = f - __builtin_bit_cast(float, hb);
    unsigned rl = __builtin_bit_cast(unsigned, rem);
    return (u >> 16) | (rl & 0xffff0000u);
}
__device__ inline float unpackhl(unsigned p) {
    return __builtin_bit_cast(float, p << 16) +
           __builtin_bit_cast(float, p & 0xffff0000u);
}

// ---------------- CSR build ----------------

__global__ __launch_bounds__(256) void hist_kernel(const int* __restrict__ dst,
                                                   int* __restrict__ counts) {
    int e = blockIdx.x * 256 + threadIdx.x;
    if (e < N_EDGES) {
        unsigned d = (unsigned)dst[e];
        if (d < N_NODES) atomicAdd(&counts[d], 1);
    }
}

__global__ __launch_bounds__(1024) void scan_kernel(const int* __restrict__ counts,
                                                    int* __restrict__ offsets) {
    __shared__ int sums[1024];
    const int t = threadIdx.x;
    const int CH = (N_NODES + 1023) / 1024;
    int lo = t * CH, hi = lo + CH;
    if (lo > N_NODES) lo = N_NODES;
    if (hi > N_NODES) hi = N_NODES;
    int s = 0;
    for (int i = lo; i < hi; ++i) s += counts[i];
    sums[t] = s;
    __syncthreads();
    for (int off = 1; off < 1024; off <<= 1) {
        int add = (t >= off) ? sums[t - off] : 0;
        __syncthreads();
        sums[t] += add;
        __syncthreads();
    }
    int run = (t > 0) ? sums[t - 1] : 0;
    for (int i = lo; i < hi; ++i) { offsets[i] = run; run += counts[i]; }
    if (hi == N_NODES) offsets[N_NODES] = run;
}

__global__ __launch_bounds__(256) void scatter_kernel(const int* __restrict__ src,
                                                      const int* __restrict__ dst,
                                                      const int* __restrict__ offsets,
                                                      int* __restrict__ cursor,
                                                      int* __restrict__ elist) {
    int e = blockIdx.x * 256 + threadIdx.x;
    if (e < N_EDGES) {
        unsigned d = (unsigned)dst[e];
        unsigned s = (unsigned)src[e];
        if (d < N_NODES && s < N_NODES) {
            int pos = offsets[d] + atomicAdd(&cursor[d], 1);
            elist[pos] = (int)s;
        }
    }
}

// ---------------- weight decompose+transpose: W[K][N] fp32 -> Wt hi/lo planes [N][K] bf16 ----

__global__ __launch_bounds__(256) void decomp_w(const float* __restrict__ W, int K, int N,
                                                ushort* __restrict__ hi, ushort* __restrict__ lo) {
    int idx = blockIdx.x * 256 + threadIdx.x;
    if (idx >= K * N) return;
    int n = idx / K, k = idx - n * K;
    float f = W[(size_t)k * N + n];
    unsigned u = __builtin_bit_cast(unsigned, f);
    unsigned hb = u & 0xffff0000u;
    float rem = f - __builtin_bit_cast(float, hb);
    hi[idx] = (ushort)(u >> 16);
    lo[idx] = (ushort)(__builtin_bit_cast(unsigned, rem) >> 16);
}

// ---------------- aggregation ----------------
// 1 node per wave; beg/end wave-uniform (readfirstlane -> scalar elist loads);
// 4-deep gather pipeline with two accumulator chains.

// x fp32 [N][128] -> out packed [N][128].  64 lanes x float2 = one 512B row.
__global__ __launch_bounds__(256) void agg_f32_pk128(const float* __restrict__ x,
                                                     const int* __restrict__ offsets,
                                                     const int* __restrict__ elist,
                                                     unsigned* __restrict__ out) {
    const int l = threadIdx.x & 63;
    const int node = blockIdx.x * 4 + (threadIdx.x >> 6);
    if (node >= N_NODES) return;
    const int beg = __builtin_amdgcn_readfirstlane(offsets[node]);
    const int end = __builtin_amdgcn_readfirstlane(offsets[node + 1]);
    float2 self = ((const float2*)(x + (size_t)node * 128))[l];
    float a0 = self.x, a1 = self.y;
    float b0 = 0.f, b1 = 0.f;
    int i = beg;
    for (; i + 4 <= end; i += 4) {
        int s0 = elist[i], s1 = elist[i + 1], s2 = elist[i + 2], s3 = elist[i + 3];
        float2 v0 = ((const float2*)(x + (size_t)s0 * 128))[l];
        float2 v1 = ((const float2*)(x + (size_t)s1 * 128))[l];
        float2 v2 = ((const float2*)(x + (size_t)s2 * 128))[l];
        float2 v3 = ((const float2*)(x + (size_t)s3 * 128))[l];
        a0 += v0.x; a1 += v0.y;
        b0 += v1.x; b1 += v1.y;
        a0 += v2.x; a1 += v2.y;
        b0 += v3.x; b1 += v3.y;
    }
    for (; i < end; ++i) {
        float2 v = ((const float2*)(x + (size_t)elist[i] * 128))[l];
        a0 += v.x; a1 += v.y;
    }
    a0 += b0; a1 += b1;
    uint2 o = make_uint2(packhl(a0), packhl(a1));
    ((uint2*)(out + (size_t)node * 128))[l] = o;
}

// packed [N][256] -> packed [N][256].  64 lanes x uint4 = one 1KB row.
__global__ __launch_bounds__(256) void agg_pk256(const unsigned* __restrict__ hin,
                                                 const int* __restrict__ offsets,
                                                 const int* __restrict__ elist,
                                                 unsigned* __restrict__ hout) {
    const int l = threadIdx.x & 63;
    const int node = blockIdx.x * 4 + (threadIdx.x >> 6);
    if (node >= N_NODES) return;
    const int beg = __builtin_amdgcn_readfirstlane(offsets[node]);
    const int end = __builtin_amdgcn_readfirstlane(offsets[node + 1]);
    uint4 p = ((const uint4*)(hin + (size_t)node * 256))[l];
    float a0 = unpackhl(p.x), a1 = unpackhl(p.y), a2 = unpackhl(p.z), a3 = unpackhl(p.w);
    float b0 = 0.f, b1 = 0.f, b2 = 0.f, b3 = 0.f;
    int i = beg;
    for (; i + 4 <= end; i += 4) {
        int s0 = elist[i], s1 = elist[i + 1], s2 = elist[i + 2], s3 = elist[i + 3];
        uint4 v0 = ((const uint4*)(hin + (size_t)s0 * 256))[l];
        uint4 v1 = ((const uint4*)(hin + (size_t)s1 * 256))[l];
        uint4 v2 = ((const uint4*)(hin + (size_t)s2 * 256))[l];
        uint4 v3 = ((const uint4*)(hin + (size_t)s3 * 256))[l];
        a0 += unpackhl(v0.x); a1 += unpackhl(v0.y); a2 += unpackhl(v0.z); a3 += unpackhl(v0.w);
        b0 += unpackhl(v1.x); b1 += unpackhl(v1.y); b2 += unpackhl(v1.z); b3 += unpackhl(v1.w);
        a0 += unpackhl(v2.x); a1 += unpackhl(v2.y); a2 += unpackhl(v2.z); a3 += unpackhl(v2.w);
        b0 += unpackhl(v3.x); b1 += unpackhl(v3.y); b2 += unpackhl(v3.z); b3 += unpackhl(v3.w);
    }
    for (; i < end; ++i) {
        uint4 v = ((const uint4*)(hin + (size_t)elist[i] * 256))[l];
        a0 += unpackhl(v.x); a1 += unpackhl(v.y); a2 += unpackhl(v.z); a3 += unpackhl(v.w);
    }
    a0 += b0; a1 += b1; a2 += b2; a3 += b3;
    uint4 o = make_uint4(packhl(a0), packhl(a1), packhl(a2), packhl(a3));
    ((uint4*)(hout + (size_t)node * 256))[l] = o;
}

// ---------------- split-bf16 MFMA GEMM ----------------
// C = [ReLU](unpack(A) @ W + b);  A packed [M][K]; W given as hi/lo planes [N][K].
// tile 128x128, BK=64, 256 threads = 4 waves (2x2), 16x16x32 bf16 MFMA, 3 passes.

template <bool RELU, bool PACKOUT>
__global__ __launch_bounds__(256, 2) void gemm_hl(const unsigned* __restrict__ Apk,
                                                  const ushort* __restrict__ Bh_g,
                                                  const ushort* __restrict__ Bl_g,
                                                  const float* __restrict__ bias,
                                                  void* __restrict__ Cout,
                                                  int M, int N, int K) {
    __shared__ ushort Ah[128 * 64], Al[128 * 64], Bh[128 * 64], Bl[128 * 64];
    const int tid = threadIdx.x;
    const int lane = tid & 63;
    const int wid = tid >> 6;
    const int wm = wid >> 1, wn = wid & 1;
    const int row0 = blockIdx.y * 128;
    const int col0 = blockIdx.x * 128;

    f32x4 acc[4][4];
#pragma unroll
    for (int i = 0; i < 4; ++i)
#pragma unroll
        for (int j = 0; j < 4; ++j) acc[i][j] = (f32x4){0.f, 0.f, 0.f, 0.f};

    for (int k0 = 0; k0 < K; k0 += 64) {
#pragma unroll
        for (int i = 0; i < 4; ++i) {
            int t = tid + i * 256;
            int row = t >> 3, kb = t & 7;
            int grow = row0 + row;
            uint4 p0 = make_uint4(0u, 0u, 0u, 0u), p1 = p0;
            if (grow < M) {
                const uint4* s = (const uint4*)(Apk + (size_t)grow * K + (k0 + kb * 8));
                p0 = s[0]; p1 = s[1];
            }
            uint4 hw, lw;
            hw.x = (p0.x & 0xffffu) | (p0.y << 16);
            lw.x = (p0.x >> 16)     | (p0.y & 0xffff0000u);
            hw.y = (p0.z & 0xffffu) | (p0.w << 16);
            lw.y = (p0.z >> 16)     | (p0.w & 0xffff0000u);
            hw.z = (p1.x & 0xffffu) | (p1.y << 16);
            lw.z = (p1.x >> 16)     | (p1.y & 0xffff0000u);
            hw.w = (p1.z & 0xffffu) | (p1.w << 16);
            lw.w = (p1.z >> 16)     | (p1.w & 0xffff0000u);
            int off = ((row * 64 + kb * 8) * 2) ^ ((row & 7) << 4);
            *(uint4*)((char*)Ah + off) = hw;
            *(uint4*)((char*)Al + off) = lw;
        }
#pragma unroll
        for (int i = 0; i < 4; ++i) {
            int t = tid + i * 256;
            int col = t >> 3, kb = t & 7;
            size_t goff = (size_t)(col0 + col) * K + (k0 + kb * 8);
            uint4 h = *(const uint4*)(Bh_g + goff);
            uint4 l2 = *(const uint4*)(Bl_g + goff);
            int off = ((col * 64 + kb * 8) * 2) ^ ((col & 7) << 4);
            *(uint4*)((char*)Bh + off) = h;
            *(uint4*)((char*)Bl + off) = l2;
        }
        __syncthreads();
#pragma unroll
        for (int ki = 0; ki < 2; ++ki) {
            bf16x8 ah[4], al[4], bh[4], bl[4];
            const int kbyte = (ki * 32 + ((lane >> 4) * 8)) * 2;
#pragma unroll
            for (int mi = 0; mi < 4; ++mi) {
                int row = wm * 64 + mi * 16 + (lane & 15);
                int off = (row * 128 + kbyte) ^ ((row & 7) << 4);
                ah[mi] = *(const bf16x8*)((const char*)Ah + off);
                al[mi] = *(const bf16x8*)((const char*)Al + off);
            }
#pragma unroll
            for (int ni = 0; ni < 4; ++ni) {
                int col = wn * 64 + ni * 16 + (lane & 15);
                int off = (col * 128 + kbyte) ^ ((col & 7) << 4);
                bh[ni] = *(const bf16x8*)((const char*)Bh + off);
                bl[ni] = *(const bf16x8*)((const char*)Bl + off);
            }
#pragma unroll
            for (int mi = 0; mi < 4; ++mi)
#pragma unroll
                for (int ni = 0; ni < 4; ++ni) {
                    acc[mi][ni] = __builtin_amdgcn_mfma_f32_16x16x32_bf16(ah[mi], bh[ni], acc[mi][ni], 0, 0, 0);
                    acc[mi][ni] = __builtin_amdgcn_mfma_f32_16x16x32_bf16(ah[mi], bl[ni], acc[mi][ni], 0, 0, 0);
                    acc[mi][ni] = __builtin_amdgcn_mfma_f32_16x16x32_bf16(al[mi], bh[ni], acc[mi][ni], 0, 0, 0);
                }
        }
        __syncthreads();
    }
#pragma unroll
    for (int ni = 0; ni < 4; ++ni) {
        int col = col0 + wn * 64 + ni * 16 + (lane & 15);
        float bv = bias[col];
#pragma unroll
        for (int mi = 0; mi < 4; ++mi) {
            int rowb = row0 + wm * 64 + mi * 16 + ((lane >> 4) << 2);
            f32x4 a = acc[mi][ni];
#pragma unroll
            for (int r = 0; r < 4; ++r) {
                int row = rowb + r;
                if (row < M) {
                    float f = a[r] + bv;
                    if (RELU) f = fmaxf(f, 0.f);
                    if (PACKOUT) ((unsigned*)Cout)[(size_t)row * N + col] = packhl(f);
                    else         ((float*)Cout)[(size_t)row * N + col] = f;
                }
            }
        }
    }
}

// ---------------- launch ----------------

extern "C" void kernel_launch(void* const* d_in, const int* in_sizes, int n_in,
                              void* d_out, int out_size, void* d_ws, size_t ws_size,
                              hipStream_t stream) {
    const float* x   = (const float*)d_in[0];
    const int*   ei  = (const int*)d_in[1];
    const float* W1a = (const float*)d_in[2];
    const float* b1a = (const float*)d_in[3];
    const float* W1b = (const float*)d_in[4];
    const float* b1b = (const float*)d_in[5];
    const float* W2a = (const float*)d_in[6];
    const float* b2a = (const float*)d_in[7];
    const float* W2b = (const float*)d_in[8];
    const float* b2b = (const float*)d_in[9];
    float* out = (float*)d_out;

    const int* src = ei;
    const int* dst = ei + N_EDGES;

    int* counts  = (int*)d_ws;
    int* cursor  = counts + N_NODES;
    int* offsets = cursor + N_NODES;
    int* elist   = offsets + (N_NODES + 1);

    size_t ob = (((size_t)(2 * N_NODES + N_NODES + 1 + N_EDGES) * 4) + 255) & ~(size_t)255;
    ushort* w1a_hi = (ushort*)((char*)d_ws + ob);
    ushort* w1a_lo = w1a_hi + 256 * 128;
    ushort* w1b_hi = w1a_lo + 256 * 128;
    ushort* w1b_lo = w1b_hi + 256 * 256;
    ushort* w2a_hi = w1b_lo + 256 * 256;
    ushort* w2a_lo = w2a_hi + 256 * 256;
    ushort* w2b_hi = w2a_lo + 256 * 256;
    ushort* w2b_lo = w2b_hi + 128 * 256;
    char*   wend   = (char*)(w2b_lo + 128 * 256);

    size_t fb = ((size_t)(wend - (char*)d_ws) + 255) & ~(size_t)255;
    unsigned* hA = (unsigned*)((char*)d_ws + fb);      // [N][256] packed
    unsigned* hB = hA + (size_t)N_NODES * 256;         // [N][256] packed
    unsigned* hC = hB + (size_t)N_NODES * 256;         // [N][256] packed
    unsigned* h0 = hC;                                 // [N][128] packed, aliased over hC

    hipMemsetAsync(counts, 0, (size_t)2 * N_NODES * sizeof(int), stream);

    const int eb = (N_EDGES + 255) / 256;
    hist_kernel<<<eb, 256, 0, stream>>>(dst, counts);
    scan_kernel<<<1, 1024, 0, stream>>>(counts, offsets);
    scatter_kernel<<<eb, 256, 0, stream>>>(src, dst, offsets, cursor, elist);

    decomp_w<<<(128 * 256 + 255) / 256, 256, 0, stream>>>(W1a, 128, 256, w1a_hi, w1a_lo);
    decomp_w<<<(256 * 256 + 255) / 256, 256, 0, stream>>>(W1b, 256, 256, w1b_hi, w1b_lo);
    decomp_w<<<(256 * 256 + 255) / 256, 256, 0, stream>>>(W2a, 256, 256, w2a_hi, w2a_lo);
    decomp_w<<<(256 * 128 + 255) / 256, 256, 0, stream>>>(W2b, 256, 128, w2b_hi, w2b_lo);

    // conv1 aggregate: h0 = pack(x + agg(x))   [N][128]
    agg_f32_pk128<<<(N_NODES + 3) / 4, 256, 0, stream>>>(x, offsets, elist, h0);
    // hA = pack(relu(h0 @ W1a + b1a))
    gemm_hl<true, true><<<dim3(2, (N_NODES + 127) / 128), 256, 0, stream>>>(
        h0, w1a_hi, w1a_lo, b1a, hA, N_NODES, 256, 128);
    // hB = pack(relu(hA @ W1b + b1b))   (outer ReLU fused)
    gemm_hl<true, true><<<dim3(2, (N_NODES + 127) / 128), 256, 0, stream>>>(
        hA, w1b_hi, w1b_lo, b1b, hB, N_NODES, 256, 256);
    // conv2 aggregate: hC = pack(hB + agg(hB))
    agg_pk256<<<(N_NODES + 3) / 4, 256, 0, stream>>>(hB, offsets, elist, hC);
    // hA = pack(relu(hC @ W2a + b2a))
    gemm_hl<true, true><<<dim3(2, (N_NODES + 127) / 128), 256, 0, stream>>>(
        hC, w2a_hi, w2a_lo, b2a, hA, N_NODES, 256, 256);
    // out = hA @ W2b + b2b   (fp32 out)
    gemm_hl<false, false><<<dim3(1, (N_NODES + 127) / 128), 256, 0, stream>>>(
        hA, w2b_hi, w2b_lo, b2b, out, N_NODES, 128, 256);
}